// Round 1
// baseline (509.344 us; speedup 1.0000x reference)
//
#include <hip/hip_runtime.h>

#define DIN 128
#define DH 64

// ---------------- degree / norm ----------------
__global__ __launch_bounds__(256) void k_init_deg(int* __restrict__ deg, int n) {
  int i = blockIdx.x * blockDim.x + threadIdx.x;
  if (i < n) deg[i] = 1;  // self-loop contributes 1
}

__global__ __launch_bounds__(256) void k_count_deg(const int* __restrict__ dst,
                                                   int* __restrict__ deg, int e) {
  int i = blockIdx.x * blockDim.x + threadIdx.x;
  if (i < e) atomicAdd(&deg[dst[i]], 1);
}

__global__ __launch_bounds__(256) void k_dinv(int* __restrict__ degbuf, int n) {
  int i = blockIdx.x * blockDim.x + threadIdx.x;
  if (i < n) {
    float d = (float)degbuf[i];
    ((float*)degbuf)[i] = rsqrtf(d);  // deg >= 1 always
  }
}

// ---------------- GEMM: [n,128] @ [128,64] ----------------
__global__ __launch_bounds__(256) void k_gemm_xw1(const float* __restrict__ x,
                                                  const float* __restrict__ W,
                                                  float* __restrict__ out, int n) {
  __shared__ float Ws[DIN * DH];       // 32 KB
  __shared__ float xs[32 * 129];       // padded stride vs bank conflicts, ~16.5 KB
  int t = threadIdx.x;
  for (int i = t; i < DIN * DH; i += 256) Ws[i] = W[i];
  int row0 = blockIdx.x * 32;
  for (int i = t; i < 32 * DIN; i += 256) {
    int r = i >> 7, c = i & 127;
    int gr = row0 + r;
    xs[r * 129 + c] = (gr < n) ? x[gr * DIN + c] : 0.f;
  }
  __syncthreads();
  int r = t >> 3;              // 32 rows, 8 threads/row
  int c0 = (t & 7) * 8;        // 8 cols each
  float acc[8] = {0, 0, 0, 0, 0, 0, 0, 0};
  for (int k = 0; k < DIN; ++k) {
    float xv = xs[r * 129 + k];
#pragma unroll
    for (int j = 0; j < 8; ++j) acc[j] = fmaf(xv, Ws[k * DH + c0 + j], acc[j]);
  }
  int gr = row0 + r;
  if (gr < n) {
#pragma unroll
    for (int j = 0; j < 8; ++j) out[gr * DH + c0 + j] = acc[j];
  }
}

// ---------------- GEMM: [n,64] @ [64,64] ----------------
__global__ __launch_bounds__(256) void k_gemm64(const float* __restrict__ in,
                                                const float* __restrict__ W,
                                                float* __restrict__ out, int n) {
  __shared__ float Ws[DH * DH];        // 16 KB
  __shared__ float xs[64 * 65];        // padded, ~16.6 KB
  int t = threadIdx.x;
  for (int i = t; i < DH * DH; i += 256) Ws[i] = W[i];
  int row0 = blockIdx.x * 64;
  for (int i = t; i < 64 * DH; i += 256) {
    int r = i >> 6, c = i & 63;
    int gr = row0 + r;
    xs[r * 65 + c] = (gr < n) ? in[gr * DH + c] : 0.f;
  }
  __syncthreads();
  int r = t >> 2;              // 64 rows, 4 threads/row
  int c0 = (t & 3) * 16;       // 16 cols each
  float acc[16];
#pragma unroll
  for (int j = 0; j < 16; ++j) acc[j] = 0.f;
  for (int k = 0; k < DH; ++k) {
    float xv = xs[r * 65 + k];
#pragma unroll
    for (int j = 0; j < 16; ++j) acc[j] = fmaf(xv, Ws[k * DH + c0 + j], acc[j]);
  }
  int gr = row0 + r;
  if (gr < n) {
#pragma unroll
    for (int j = 0; j < 16; ++j) out[gr * DH + c0 + j] = acc[j];
  }
}

// ---------------- self-loop init: out[i,:] = in[i,:] * dinv[i]^2 ----------------
__global__ __launch_bounds__(256) void k_scale_self(const float* __restrict__ in,
                                                    const float* __restrict__ dinv,
                                                    float* __restrict__ out, int total) {
  int i = blockIdx.x * blockDim.x + threadIdx.x;
  if (i < total) {
    float di = dinv[i >> 6];
    out[i] = in[i] * di * di;
  }
}

// ---------------- edge scatter: agg[dst,:] += h[src,:]*dinv[src]*dinv[dst] ----------------
__global__ __launch_bounds__(256) void k_edge_scatter(const int* __restrict__ src,
                                                      const int* __restrict__ dst,
                                                      const float* __restrict__ dinv,
                                                      const float* __restrict__ h,
                                                      float* __restrict__ agg, int e) {
  int idx = blockIdx.x * 4 + (threadIdx.x >> 6);  // 4 edges per 256-thread block
  int d = threadIdx.x & 63;
  if (idx >= e) return;
  int s = src[idx];
  int t = dst[idx];
  float norm = dinv[s] * dinv[t];
  atomicAdd(&agg[t * DH + d], h[s * DH + d] * norm);
}

// ---------------- bias (+optional relu), in place ----------------
__global__ __launch_bounds__(256) void k_bias_relu(float* __restrict__ a,
                                                   const float* __restrict__ b, int total) {
  int i = blockIdx.x * blockDim.x + threadIdx.x;
  if (i < total) a[i] = fmaxf(a[i] + b[i & 63], 0.f);
}

__global__ __launch_bounds__(256) void k_bias(float* __restrict__ a,
                                              const float* __restrict__ b, int total) {
  int i = blockIdx.x * blockDim.x + threadIdx.x;
  if (i < total) a[i] = a[i] + b[i & 63];
}

// ---------------- fused MLP head: p = relu(z@Wp1+bp1)@Wp2+bp2 ----------------
__global__ __launch_bounds__(256) void k_mlp(const float* __restrict__ z,
                                             const float* __restrict__ Wp1,
                                             const float* __restrict__ bp1,
                                             const float* __restrict__ Wp2,
                                             const float* __restrict__ bp2,
                                             float* __restrict__ p, int n) {
  __shared__ float W1s[DH * DH];   // 16 KB
  __shared__ float W2s[DH * DH];   // 16 KB
  __shared__ float xs[64 * 65];    // z tile, then reused for T tile
  __shared__ float b1s[64], b2s[64];
  int t = threadIdx.x;
  for (int i = t; i < DH * DH; i += 256) { W1s[i] = Wp1[i]; W2s[i] = Wp2[i]; }
  if (t < 64) { b1s[t] = bp1[t]; b2s[t] = bp2[t]; }
  int row0 = blockIdx.x * 64;
  for (int i = t; i < 64 * DH; i += 256) {
    int r = i >> 6, c = i & 63;
    int gr = row0 + r;
    xs[r * 65 + c] = (gr < n) ? z[gr * DH + c] : 0.f;
  }
  __syncthreads();
  int r = t >> 2;
  int c0 = (t & 3) * 16;
  float acc[16];
#pragma unroll
  for (int j = 0; j < 16; ++j) acc[j] = b1s[c0 + j];
  for (int k = 0; k < DH; ++k) {
    float xv = xs[r * 65 + k];
#pragma unroll
    for (int j = 0; j < 16; ++j) acc[j] = fmaf(xv, W1s[k * DH + c0 + j], acc[j]);
  }
  __syncthreads();  // all reads of xs (z tile) complete
#pragma unroll
  for (int j = 0; j < 16; ++j) xs[r * 65 + c0 + j] = fmaxf(acc[j], 0.f);
  __syncthreads();
#pragma unroll
  for (int j = 0; j < 16; ++j) acc[j] = b2s[c0 + j];
  for (int k = 0; k < DH; ++k) {
    float xv = xs[r * 65 + k];
#pragma unroll
    for (int j = 0; j < 16; ++j) acc[j] = fmaf(xv, W2s[k * DH + c0 + j], acc[j]);
  }
  int gr = row0 + r;
  if (gr < n) {
#pragma unroll
    for (int j = 0; j < 16; ++j) p[gr * DH + c0 + j] = acc[j];
  }
}

extern "C" void kernel_launch(void* const* d_in, const int* in_sizes, int n_in,
                              void* d_out, int out_size, void* d_ws, size_t ws_size,
                              hipStream_t stream) {
  const float* x   = (const float*)d_in[0];
  const int*   ei  = (const int*)d_in[1];
  const float* W1  = (const float*)d_in[2];
  const float* b1  = (const float*)d_in[3];
  const float* W2  = (const float*)d_in[4];
  const float* b2  = (const float*)d_in[5];
  const float* Wp1 = (const float*)d_in[6];
  const float* bp1 = (const float*)d_in[7];
  const float* Wp2 = (const float*)d_in[8];
  const float* bp2 = (const float*)d_in[9];

  int n = in_sizes[0] / DIN;   // 50000
  int e = in_sizes[1] / 2;     // 800000
  const int* src = ei;
  const int* dst = ei + e;

  float* bufA = (float*)d_ws;                              // n*64 f32 = 12.8 MB (h1, then h2)
  int*   deg  = (int*)((char*)d_ws + ((size_t)13 << 20));  // n i32 -> becomes dinv f32 in place
  float* dinv = (float*)deg;

  float* zout = (float*)d_out;                 // [n,64] final z
  float* pout = zout + (size_t)n * DH;         // [n,64]; used as agg1/h scratch, then final p

  int total = n * DH;
  int gElem = (total + 255) / 256;

  // degree + dinv
  k_init_deg<<<(n + 255) / 256, 256, 0, stream>>>(deg, n);
  k_count_deg<<<(e + 255) / 256, 256, 0, stream>>>(dst, deg, e);
  k_dinv<<<(n + 255) / 256, 256, 0, stream>>>(deg, n);

  // layer 1: h1 = x@W1 ; h = relu(agg(h1) + b1)  (h lives in pout)
  k_gemm_xw1<<<(n + 31) / 32, 256, 0, stream>>>(x, W1, bufA, n);
  k_scale_self<<<gElem, 256, 0, stream>>>(bufA, dinv, pout, total);
  k_edge_scatter<<<(e + 3) / 4, 256, 0, stream>>>(src, dst, dinv, bufA, pout, e);
  k_bias_relu<<<gElem, 256, 0, stream>>>(pout, b1, total);

  // layer 2: h2 = h@W2 ; z = agg(h2) + b2  (z lives in zout = d_out)
  k_gemm64<<<(n + 63) / 64, 256, 0, stream>>>(pout, W2, bufA, n);
  k_scale_self<<<gElem, 256, 0, stream>>>(bufA, dinv, zout, total);
  k_edge_scatter<<<(e + 3) / 4, 256, 0, stream>>>(src, dst, dinv, bufA, zout, e);
  k_bias<<<gElem, 256, 0, stream>>>(zout, b2, total);

  // head: p = relu(z@Wp1+bp1)@Wp2+bp2  (overwrites pout scratch)
  k_mlp<<<(n + 63) / 64, 256, 0, stream>>>(zout, Wp1, bp1, Wp2, bp2, pout, n);
}

// Round 2
// 321.462 us; speedup vs baseline: 1.5845x; 1.5845x over previous
//
#include <hip/hip_runtime.h>

#define DIN 128
#define DH 64

// ---------------- degree / norm ----------------
__global__ __launch_bounds__(256) void k_init_i32(int* __restrict__ p, int v, int n) {
  int i = blockIdx.x * blockDim.x + threadIdx.x;
  if (i < n) p[i] = v;
}

__global__ __launch_bounds__(256) void k_count_deg(const int* __restrict__ dst,
                                                   int* __restrict__ deg, int e) {
  int i = blockIdx.x * blockDim.x + threadIdx.x;
  if (i < e) atomicAdd(&deg[dst[i]], 1);
}

// exclusive scan of (deg[i]-1) over n elements, single 1024-thread block
__global__ __launch_bounds__(1024) void k_scan(const int* __restrict__ deg,
                                               int* __restrict__ off, int n) {
  __shared__ int sums[1024];
  int t = threadIdx.x;
  int chunk = (n + 1023) / 1024;
  int s0 = t * chunk;
  int s1 = s0 + chunk; if (s1 > n) s1 = n; if (s0 > n) s0 = n;
  int sum = 0;
  for (int i = s0; i < s1; ++i) sum += deg[i] - 1;
  sums[t] = sum;
  __syncthreads();
  for (int ofs = 1; ofs < 1024; ofs <<= 1) {
    int v = (t >= ofs) ? sums[t - ofs] : 0;
    __syncthreads();
    sums[t] += v;
    __syncthreads();
  }
  int run = (t > 0) ? sums[t - 1] : 0;
  for (int i = s0; i < s1; ++i) { off[i] = run; run += deg[i] - 1; }
  if (t == 1023) off[n] = sums[1023];
}

__global__ __launch_bounds__(256) void k_dinv(int* __restrict__ degbuf, int n) {
  int i = blockIdx.x * blockDim.x + threadIdx.x;
  if (i < n) {
    float d = (float)degbuf[i];
    ((float*)degbuf)[i] = rsqrtf(d);  // deg >= 1 always (self-loop)
  }
}

// bucket edges by dst: srcs[off[d] + cur[d]++] = src
__global__ __launch_bounds__(256) void k_fill(const int* __restrict__ src,
                                              const int* __restrict__ dst,
                                              const int* __restrict__ off,
                                              int* __restrict__ cur,
                                              int* __restrict__ srcs, int e) {
  int i = blockIdx.x * blockDim.x + threadIdx.x;
  if (i < e) {
    int d = dst[i];
    int pos = off[d] + atomicAdd(&cur[d], 1);
    srcs[pos] = src[i];
  }
}

// ---------------- GEMM: [n,128] @ [128,64] ----------------
__global__ __launch_bounds__(256) void k_gemm_xw1(const float* __restrict__ x,
                                                  const float* __restrict__ W,
                                                  float* __restrict__ out, int n) {
  __shared__ float Ws[DIN * DH];
  __shared__ float xs[32 * 129];
  int t = threadIdx.x;
  for (int i = t; i < DIN * DH; i += 256) Ws[i] = W[i];
  int row0 = blockIdx.x * 32;
  for (int i = t; i < 32 * DIN; i += 256) {
    int r = i >> 7, c = i & 127;
    int gr = row0 + r;
    xs[r * 129 + c] = (gr < n) ? x[gr * DIN + c] : 0.f;
  }
  __syncthreads();
  int r = t >> 3;
  int c0 = (t & 7) * 8;
  float acc[8] = {0, 0, 0, 0, 0, 0, 0, 0};
  for (int k = 0; k < DIN; ++k) {
    float xv = xs[r * 129 + k];
#pragma unroll
    for (int j = 0; j < 8; ++j) acc[j] = fmaf(xv, Ws[k * DH + c0 + j], acc[j]);
  }
  int gr = row0 + r;
  if (gr < n) {
#pragma unroll
    for (int j = 0; j < 8; ++j) out[gr * DH + c0 + j] = acc[j];
  }
}

// ---------------- GEMM: [n,64] @ [64,64] ----------------
__global__ __launch_bounds__(256) void k_gemm64(const float* __restrict__ in,
                                                const float* __restrict__ W,
                                                float* __restrict__ out, int n) {
  __shared__ float Ws[DH * DH];
  __shared__ float xs[64 * 65];
  int t = threadIdx.x;
  for (int i = t; i < DH * DH; i += 256) Ws[i] = W[i];
  int row0 = blockIdx.x * 64;
  for (int i = t; i < 64 * DH; i += 256) {
    int r = i >> 6, c = i & 63;
    int gr = row0 + r;
    xs[r * 65 + c] = (gr < n) ? in[gr * DH + c] : 0.f;
  }
  __syncthreads();
  int r = t >> 2;
  int c0 = (t & 3) * 16;
  float acc[16];
#pragma unroll
  for (int j = 0; j < 16; ++j) acc[j] = 0.f;
  for (int k = 0; k < DH; ++k) {
    float xv = xs[r * 65 + k];
#pragma unroll
    for (int j = 0; j < 16; ++j) acc[j] = fmaf(xv, Ws[k * DH + c0 + j], acc[j]);
  }
  int gr = row0 + r;
  if (gr < n) {
#pragma unroll
    for (int j = 0; j < 16; ++j) out[gr * DH + c0 + j] = acc[j];
  }
}

// ---------------- CSR gather-aggregate, fused self-loop + bias (+relu) ------
// wave per node, lane = feature dim
__global__ __launch_bounds__(256) void k_agg(const float* __restrict__ h,
                                             const int* __restrict__ off,
                                             const int* __restrict__ srcs,
                                             const float* __restrict__ dinv,
                                             const float* __restrict__ bias,
                                             float* __restrict__ out, int n, int relu) {
  int gid = blockIdx.x * 4 + (threadIdx.x >> 6);
  int d = threadIdx.x & 63;
  if (gid >= n) return;
  gid = __builtin_amdgcn_readfirstlane(gid);  // wave-uniform -> scalar loads below
  float di = dinv[gid];
  float acc = h[(size_t)gid * DH + d] * di * di;  // self-loop
  int b0 = off[gid], b1 = off[gid + 1];
  int j = b0;
  for (; j + 4 <= b1; j += 4) {
    int s0 = srcs[j], s1 = srcs[j + 1], s2 = srcs[j + 2], s3 = srcs[j + 3];
    float w0 = dinv[s0] * di, w1 = dinv[s1] * di, w2 = dinv[s2] * di, w3 = dinv[s3] * di;
    float v0 = h[(size_t)s0 * DH + d];
    float v1 = h[(size_t)s1 * DH + d];
    float v2 = h[(size_t)s2 * DH + d];
    float v3 = h[(size_t)s3 * DH + d];
    acc = fmaf(v0, w0, acc);
    acc = fmaf(v1, w1, acc);
    acc = fmaf(v2, w2, acc);
    acc = fmaf(v3, w3, acc);
  }
  for (; j < b1; ++j) {
    int s = srcs[j];
    acc = fmaf(h[(size_t)s * DH + d], dinv[s] * di, acc);
  }
  acc += bias[d];
  if (relu) acc = fmaxf(acc, 0.f);
  out[(size_t)gid * DH + d] = acc;
}

// ---------------- fused MLP head: p = relu(z@Wp1+bp1)@Wp2+bp2 ----------------
__global__ __launch_bounds__(256) void k_mlp(const float* __restrict__ z,
                                             const float* __restrict__ Wp1,
                                             const float* __restrict__ bp1,
                                             const float* __restrict__ Wp2,
                                             const float* __restrict__ bp2,
                                             float* __restrict__ p, int n) {
  __shared__ float W1s[DH * DH];
  __shared__ float W2s[DH * DH];
  __shared__ float xs[64 * 65];
  __shared__ float b1s[64], b2s[64];
  int t = threadIdx.x;
  for (int i = t; i < DH * DH; i += 256) { W1s[i] = Wp1[i]; W2s[i] = Wp2[i]; }
  if (t < 64) { b1s[t] = bp1[t]; b2s[t] = bp2[t]; }
  int row0 = blockIdx.x * 64;
  for (int i = t; i < 64 * DH; i += 256) {
    int r = i >> 6, c = i & 63;
    int gr = row0 + r;
    xs[r * 65 + c] = (gr < n) ? z[gr * DH + c] : 0.f;
  }
  __syncthreads();
  int r = t >> 2;
  int c0 = (t & 3) * 16;
  float acc[16];
#pragma unroll
  for (int j = 0; j < 16; ++j) acc[j] = b1s[c0 + j];
  for (int k = 0; k < DH; ++k) {
    float xv = xs[r * 65 + k];
#pragma unroll
    for (int j = 0; j < 16; ++j) acc[j] = fmaf(xv, W1s[k * DH + c0 + j], acc[j]);
  }
  __syncthreads();
#pragma unroll
  for (int j = 0; j < 16; ++j) xs[r * 65 + c0 + j] = fmaxf(acc[j], 0.f);
  __syncthreads();
#pragma unroll
  for (int j = 0; j < 16; ++j) acc[j] = b2s[c0 + j];
  for (int k = 0; k < DH; ++k) {
    float xv = xs[r * 65 + k];
#pragma unroll
    for (int j = 0; j < 16; ++j) acc[j] = fmaf(xv, W2s[k * DH + c0 + j], acc[j]);
  }
  int gr = row0 + r;
  if (gr < n) {
#pragma unroll
    for (int j = 0; j < 16; ++j) p[gr * DH + c0 + j] = acc[j];
  }
}

extern "C" void kernel_launch(void* const* d_in, const int* in_sizes, int n_in,
                              void* d_out, int out_size, void* d_ws, size_t ws_size,
                              hipStream_t stream) {
  const float* x   = (const float*)d_in[0];
  const int*   ei  = (const int*)d_in[1];
  const float* W1  = (const float*)d_in[2];
  const float* b1  = (const float*)d_in[3];
  const float* W2  = (const float*)d_in[4];
  const float* b2  = (const float*)d_in[5];
  const float* Wp1 = (const float*)d_in[6];
  const float* bp1 = (const float*)d_in[7];
  const float* Wp2 = (const float*)d_in[8];
  const float* bp2 = (const float*)d_in[9];

  int n = in_sizes[0] / DIN;   // 50000
  int e = in_sizes[1] / 2;     // 800000
  const int* src = ei;
  const int* dst = ei + e;

  // workspace layout
  char* ws = (char*)d_ws;
  float* bufA = (float*)ws;                                  // n*64 f32 = 12.8 MB
  int*   off  = (int*)(ws + ((size_t)13 << 20));             // (n+1) i32
  int*   deg  = (int*)(ws + ((size_t)13 << 20) + (1 << 18)); // n i32 -> dinv f32 in place
  int*   cur  = (int*)(ws + ((size_t)13 << 20) + (2 << 18)); // n i32
  int*   srcs = (int*)(ws + ((size_t)13 << 20) + (3 << 18)); // e i32 = 3.2 MB
  float* dinv = (float*)deg;

  float* zout = (float*)d_out;
  float* pout = zout + (size_t)n * DH;  // scratch for h, then final p

  // ---- CSR build (shared by both layers) ----
  k_init_i32<<<(n + 255) / 256, 256, 0, stream>>>(deg, 1, n);
  k_count_deg<<<(e + 255) / 256, 256, 0, stream>>>(dst, deg, e);
  k_scan<<<1, 1024, 0, stream>>>(deg, off, n);
  k_dinv<<<(n + 255) / 256, 256, 0, stream>>>(deg, n);
  k_init_i32<<<(n + 255) / 256, 256, 0, stream>>>(cur, 0, n);
  k_fill<<<(e + 255) / 256, 256, 0, stream>>>(src, dst, off, cur, srcs, e);

  // ---- layer 1: h = relu(agg(x@W1) + b1) -> pout ----
  k_gemm_xw1<<<(n + 31) / 32, 256, 0, stream>>>(x, W1, bufA, n);
  k_agg<<<(n + 3) / 4, 256, 0, stream>>>(bufA, off, srcs, dinv, b1, pout, n, 1);

  // ---- layer 2: z = agg(h@W2) + b2 -> zout ----
  k_gemm64<<<(n + 63) / 64, 256, 0, stream>>>(pout, W2, bufA, n);
  k_agg<<<(n + 3) / 4, 256, 0, stream>>>(bufA, off, srcs, dinv, b2, zout, n, 0);

  // ---- head: p = relu(z@Wp1+bp1)@Wp2+bp2 ----
  k_mlp<<<(n + 63) / 64, 256, 0, stream>>>(zout, Wp1, bp1, Wp2, bp2, pout, n);
}

// Round 3
// 249.569 us; speedup vs baseline: 2.0409x; 1.2881x over previous
//
#include <hip/hip_runtime.h>

#define DIN 128
#define DH 64
#define SCAN_TILE 1024  // elements per scan block (256 threads x 4)

// ---------------- degree / norm ----------------
__global__ __launch_bounds__(256) void k_init_i32(int* __restrict__ p, int v, int n) {
  int i = blockIdx.x * blockDim.x + threadIdx.x;
  if (i < n) p[i] = v;
}

__global__ __launch_bounds__(256) void k_count_deg(const int* __restrict__ dst,
                                                   int* __restrict__ deg, int e) {
  int i = blockIdx.x * blockDim.x + threadIdx.x;
  if (i < e) atomicAdd(&deg[dst[i]], 1);
}

// ---- hierarchical exclusive scan of (deg[i]-1) ----
// pass 1: per-block sums
__global__ __launch_bounds__(256) void k_scan_part(const int* __restrict__ deg,
                                                   int* __restrict__ partials, int n) {
  __shared__ int red[256];
  int t = threadIdx.x;
  int base = blockIdx.x * SCAN_TILE + t * 4;
  int s = 0;
#pragma unroll
  for (int j = 0; j < 4; ++j) {
    int i = base + j;
    if (i < n) s += deg[i] - 1;
  }
  red[t] = s;
  __syncthreads();
  for (int ofs = 128; ofs > 0; ofs >>= 1) {
    if (t < ofs) red[t] += red[t + ofs];
    __syncthreads();
  }
  if (t == 0) partials[blockIdx.x] = red[0];
}

// pass 2: exclusive scan of partials (nb <= 64), one wave
__global__ __launch_bounds__(64) void k_scan_mid(int* __restrict__ partials, int nb) {
  __shared__ int s[64];
  int t = threadIdx.x;
  s[t] = (t < nb) ? partials[t] : 0;
  __syncthreads();
  int v = s[t];
  for (int ofs = 1; ofs < 64; ofs <<= 1) {
    int u = (t >= ofs) ? s[t - ofs] : 0;
    __syncthreads();
    s[t] += u;
    __syncthreads();
  }
  if (t < nb) partials[t] = s[t] - v;  // exclusive
}

// pass 3: local exclusive scan + block base; fuses dinv + cur init
__global__ __launch_bounds__(256) void k_scan_add(const int* __restrict__ deg,
                                                  const int* __restrict__ partials,
                                                  int* __restrict__ off,
                                                  float* __restrict__ dinv,
                                                  int* __restrict__ cur, int n, int e) {
  __shared__ int red[256];
  int t = threadIdx.x;
  int base = blockIdx.x * SCAN_TILE + t * 4;
  int d[4];
  int s = 0;
#pragma unroll
  for (int j = 0; j < 4; ++j) {
    int i = base + j;
    d[j] = (i < n) ? deg[i] - 1 : 0;
    s += d[j];
  }
  red[t] = s;
  __syncthreads();
  int incl = s;
  for (int ofs = 1; ofs < 256; ofs <<= 1) {
    int u = (t >= ofs) ? red[t - ofs] : 0;
    __syncthreads();
    red[t] += u;
    __syncthreads();
    incl = red[t];
  }
  int run = partials[blockIdx.x] + incl - s;  // exclusive start for this thread
#pragma unroll
  for (int j = 0; j < 4; ++j) {
    int i = base + j;
    if (i < n) {
      off[i] = run;
      run += d[j];
      dinv[i] = rsqrtf((float)(d[j] + 1));
      cur[i] = 0;
    }
  }
  if (blockIdx.x == 0 && t == 0) off[n] = e;  // sum(deg-1) == e
}

// bucket edges by dst: srcs[off[d] + cur[d]++] = src
__global__ __launch_bounds__(256) void k_fill(const int* __restrict__ src,
                                              const int* __restrict__ dst,
                                              const int* __restrict__ off,
                                              int* __restrict__ cur,
                                              int* __restrict__ srcs, int e) {
  int i = blockIdx.x * blockDim.x + threadIdx.x;
  if (i < e) {
    int d = dst[i];
    int pos = off[d] + atomicAdd(&cur[d], 1);
    srcs[pos] = src[i];
  }
}

// ---------------- GEMM: [n,128] @ [128,64] ----------------
__global__ __launch_bounds__(256) void k_gemm_xw1(const float* __restrict__ x,
                                                  const float* __restrict__ W,
                                                  float* __restrict__ out, int n) {
  __shared__ float Ws[DIN * DH];
  __shared__ float xs[32 * 129];
  int t = threadIdx.x;
  for (int i = t; i < DIN * DH; i += 256) Ws[i] = W[i];
  int row0 = blockIdx.x * 32;
  for (int i = t; i < 32 * DIN; i += 256) {
    int r = i >> 7, c = i & 127;
    int gr = row0 + r;
    xs[r * 129 + c] = (gr < n) ? x[gr * DIN + c] : 0.f;
  }
  __syncthreads();
  int r = t >> 3;
  int c0 = (t & 7) * 8;
  float acc[8] = {0, 0, 0, 0, 0, 0, 0, 0};
  for (int k = 0; k < DIN; ++k) {
    float xv = xs[r * 129 + k];
#pragma unroll
    for (int j = 0; j < 8; ++j) acc[j] = fmaf(xv, Ws[k * DH + c0 + j], acc[j]);
  }
  int gr = row0 + r;
  if (gr < n) {
#pragma unroll
    for (int j = 0; j < 8; ++j) out[gr * DH + c0 + j] = acc[j];
  }
}

// ---------------- GEMM: [n,64] @ [64,64] ----------------
__global__ __launch_bounds__(256) void k_gemm64(const float* __restrict__ in,
                                                const float* __restrict__ W,
                                                float* __restrict__ out, int n) {
  __shared__ float Ws[DH * DH];
  __shared__ float xs[64 * 65];
  int t = threadIdx.x;
  for (int i = t; i < DH * DH; i += 256) Ws[i] = W[i];
  int row0 = blockIdx.x * 64;
  for (int i = t; i < 64 * DH; i += 256) {
    int r = i >> 6, c = i & 63;
    int gr = row0 + r;
    xs[r * 65 + c] = (gr < n) ? in[gr * DH + c] : 0.f;
  }
  __syncthreads();
  int r = t >> 2;
  int c0 = (t & 3) * 16;
  float acc[16];
#pragma unroll
  for (int j = 0; j < 16; ++j) acc[j] = 0.f;
  for (int k = 0; k < DH; ++k) {
    float xv = xs[r * 65 + k];
#pragma unroll
    for (int j = 0; j < 16; ++j) acc[j] = fmaf(xv, Ws[k * DH + c0 + j], acc[j]);
  }
  int gr = row0 + r;
  if (gr < n) {
#pragma unroll
    for (int j = 0; j < 16; ++j) out[gr * DH + c0 + j] = acc[j];
  }
}

// ---------------- CSR gather-aggregate, fused self-loop + bias (+relu) ------
__global__ __launch_bounds__(256) void k_agg(const float* __restrict__ h,
                                             const int* __restrict__ off,
                                             const int* __restrict__ srcs,
                                             const float* __restrict__ dinv,
                                             const float* __restrict__ bias,
                                             float* __restrict__ out, int n, int relu) {
  int gid = blockIdx.x * 4 + (threadIdx.x >> 6);
  int d = threadIdx.x & 63;
  if (gid >= n) return;
  gid = __builtin_amdgcn_readfirstlane(gid);
  float di = dinv[gid];
  float acc = h[(size_t)gid * DH + d] * di * di;
  int b0 = off[gid], b1 = off[gid + 1];
  int j = b0;
  for (; j + 4 <= b1; j += 4) {
    int s0 = srcs[j], s1 = srcs[j + 1], s2 = srcs[j + 2], s3 = srcs[j + 3];
    float w0 = dinv[s0] * di, w1 = dinv[s1] * di, w2 = dinv[s2] * di, w3 = dinv[s3] * di;
    float v0 = h[(size_t)s0 * DH + d];
    float v1 = h[(size_t)s1 * DH + d];
    float v2 = h[(size_t)s2 * DH + d];
    float v3 = h[(size_t)s3 * DH + d];
    acc = fmaf(v0, w0, acc);
    acc = fmaf(v1, w1, acc);
    acc = fmaf(v2, w2, acc);
    acc = fmaf(v3, w3, acc);
  }
  for (; j < b1; ++j) {
    int s = srcs[j];
    acc = fmaf(h[(size_t)s * DH + d], dinv[s] * di, acc);
  }
  acc += bias[d];
  if (relu) acc = fmaxf(acc, 0.f);
  out[(size_t)gid * DH + d] = acc;
}

// ---------------- fused MLP head ----------------
__global__ __launch_bounds__(256) void k_mlp(const float* __restrict__ z,
                                             const float* __restrict__ Wp1,
                                             const float* __restrict__ bp1,
                                             const float* __restrict__ Wp2,
                                             const float* __restrict__ bp2,
                                             float* __restrict__ p, int n) {
  __shared__ float W1s[DH * DH];
  __shared__ float W2s[DH * DH];
  __shared__ float xs[64 * 65];
  __shared__ float b1s[64], b2s[64];
  int t = threadIdx.x;
  for (int i = t; i < DH * DH; i += 256) { W1s[i] = Wp1[i]; W2s[i] = Wp2[i]; }
  if (t < 64) { b1s[t] = bp1[t]; b2s[t] = bp2[t]; }
  int row0 = blockIdx.x * 64;
  for (int i = t; i < 64 * DH; i += 256) {
    int r = i >> 6, c = i & 63;
    int gr = row0 + r;
    xs[r * 65 + c] = (gr < n) ? z[gr * DH + c] : 0.f;
  }
  __syncthreads();
  int r = t >> 2;
  int c0 = (t & 3) * 16;
  float acc[16];
#pragma unroll
  for (int j = 0; j < 16; ++j) acc[j] = b1s[c0 + j];
  for (int k = 0; k < DH; ++k) {
    float xv = xs[r * 65 + k];
#pragma unroll
    for (int j = 0; j < 16; ++j) acc[j] = fmaf(xv, W1s[k * DH + c0 + j], acc[j]);
  }
  __syncthreads();
#pragma unroll
  for (int j = 0; j < 16; ++j) xs[r * 65 + c0 + j] = fmaxf(acc[j], 0.f);
  __syncthreads();
#pragma unroll
  for (int j = 0; j < 16; ++j) acc[j] = b2s[c0 + j];
  for (int k = 0; k < DH; ++k) {
    float xv = xs[r * 65 + k];
#pragma unroll
    for (int j = 0; j < 16; ++j) acc[j] = fmaf(xv, W2s[k * DH + c0 + j], acc[j]);
  }
  int gr = row0 + r;
  if (gr < n) {
#pragma unroll
    for (int j = 0; j < 16; ++j) p[gr * DH + c0 + j] = acc[j];
  }
}

extern "C" void kernel_launch(void* const* d_in, const int* in_sizes, int n_in,
                              void* d_out, int out_size, void* d_ws, size_t ws_size,
                              hipStream_t stream) {
  const float* x   = (const float*)d_in[0];
  const int*   ei  = (const int*)d_in[1];
  const float* W1  = (const float*)d_in[2];
  const float* b1  = (const float*)d_in[3];
  const float* W2  = (const float*)d_in[4];
  const float* b2  = (const float*)d_in[5];
  const float* Wp1 = (const float*)d_in[6];
  const float* bp1 = (const float*)d_in[7];
  const float* Wp2 = (const float*)d_in[8];
  const float* bp2 = (const float*)d_in[9];

  int n = in_sizes[0] / DIN;   // 50000
  int e = in_sizes[1] / 2;     // 800000
  const int* src = ei;
  const int* dst = ei + e;

  // workspace layout
  char* ws = (char*)d_ws;
  float* bufA  = (float*)ws;                                  // n*64 f32 = 12.8 MB
  int*   off   = (int*)(ws + ((size_t)13 << 20));             // (n+1) i32
  int*   deg   = (int*)(ws + ((size_t)13 << 20) + (1 << 18)); // n i32
  int*   cur   = (int*)(ws + ((size_t)13 << 20) + (2 << 18)); // n i32
  float* dinv  = (float*)(ws + ((size_t)13 << 20) + (3 << 18)); // n f32
  int*   parts = (int*)(ws + ((size_t)13 << 20) + (4 << 18)); // scan partials
  int*   srcs  = (int*)(ws + ((size_t)13 << 20) + (5 << 18)); // e i32 = 3.2 MB

  float* zout = (float*)d_out;
  float* pout = zout + (size_t)n * DH;

  int nb = (n + SCAN_TILE - 1) / SCAN_TILE;  // 49

  // ---- CSR build ----
  k_init_i32<<<(n + 255) / 256, 256, 0, stream>>>(deg, 1, n);
  k_count_deg<<<(e + 255) / 256, 256, 0, stream>>>(dst, deg, e);
  k_scan_part<<<nb, 256, 0, stream>>>(deg, parts, n);
  k_scan_mid<<<1, 64, 0, stream>>>(parts, nb);
  k_scan_add<<<nb, 256, 0, stream>>>(deg, parts, off, dinv, cur, n, e);
  k_fill<<<(e + 255) / 256, 256, 0, stream>>>(src, dst, off, cur, srcs, e);

  // ---- layer 1 ----
  k_gemm_xw1<<<(n + 31) / 32, 256, 0, stream>>>(x, W1, bufA, n);
  k_agg<<<(n + 3) / 4, 256, 0, stream>>>(bufA, off, srcs, dinv, b1, pout, n, 1);

  // ---- layer 2 ----
  k_gemm64<<<(n + 63) / 64, 256, 0, stream>>>(pout, W2, bufA, n);
  k_agg<<<(n + 3) / 4, 256, 0, stream>>>(bufA, off, srcs, dinv, b2, zout, n, 0);

  // ---- head ----
  k_mlp<<<(n + 63) / 64, 256, 0, stream>>>(zout, Wp1, bp1, Wp2, bp2, pout, n);
}

// Round 4
// 200.318 us; speedup vs baseline: 2.5427x; 1.2459x over previous
//
#include <hip/hip_runtime.h>

#define DIN 128
#define DH 64
#define SCAN_TILE 1024
#define NBINS 512      // bin = dst >> 7 ; n=50000 -> bins 0..390 used
#define BIN_SHIFT 7
#define BIN_NODES 128
#define ETILE 4096     // edges per histogram/scatter block

// ---------------- binning pass A: per-block histogram ----------------
__global__ __launch_bounds__(256) void k_hist(const int* __restrict__ dst,
                                              int* __restrict__ histMat, int e, int nblk) {
  __shared__ int h[NBINS];
  int t = threadIdx.x;
  for (int i = t; i < NBINS; i += 256) h[i] = 0;
  __syncthreads();
  int base = blockIdx.x * ETILE;
  for (int i = base + t; i < base + ETILE; i += 256)
    if (i < e) atomicAdd(&h[dst[i] >> BIN_SHIFT], 1);
  __syncthreads();
  for (int i = t; i < NBINS; i += 256) histMat[i * nblk + blockIdx.x] = h[i];
}

// ---------------- generic hierarchical exclusive scan ----------------
__global__ __launch_bounds__(256) void k_scan_part(const int* __restrict__ in,
                                                   int* __restrict__ partials, int n) {
  __shared__ int red[256];
  int t = threadIdx.x;
  int base = blockIdx.x * SCAN_TILE + t * 4;
  int s = 0;
#pragma unroll
  for (int j = 0; j < 4; ++j) { int i = base + j; if (i < n) s += in[i]; }
  red[t] = s;
  __syncthreads();
  for (int ofs = 128; ofs > 0; ofs >>= 1) {
    if (t < ofs) red[t] += red[t + ofs];
    __syncthreads();
  }
  if (t == 0) partials[blockIdx.x] = red[0];
}

__global__ __launch_bounds__(256) void k_scan_mid(int* __restrict__ partials, int nb) {
  __shared__ int sm[256];
  int t = threadIdx.x;
  int v = (t < nb) ? partials[t] : 0;
  sm[t] = v;
  __syncthreads();
  for (int ofs = 1; ofs < 256; ofs <<= 1) {
    int u = (t >= ofs) ? sm[t - ofs] : 0;
    __syncthreads();
    sm[t] += u;
    __syncthreads();
  }
  if (t < nb) partials[t] = sm[t] - v;  // exclusive
}

// in-place exclusive-scan emit (reads complete before writes within each tile)
__global__ __launch_bounds__(256) void k_scan_emit(int* __restrict__ data,
                                                   const int* __restrict__ partials, int n) {
  __shared__ int red[256];
  int t = threadIdx.x;
  int base = blockIdx.x * SCAN_TILE + t * 4;
  int d[4];
  int s = 0;
#pragma unroll
  for (int j = 0; j < 4; ++j) { int i = base + j; d[j] = (i < n) ? data[i] : 0; s += d[j]; }
  red[t] = s;
  __syncthreads();
  int incl = s;
  for (int ofs = 1; ofs < 256; ofs <<= 1) {
    int u = (t >= ofs) ? red[t - ofs] : 0;
    __syncthreads();
    red[t] += u;
    __syncthreads();
    incl = red[t];
  }
  int run = partials[blockIdx.x] + incl - s;
#pragma unroll
  for (int j = 0; j < 4; ++j) {
    int i = base + j;
    if (i < n) { data[i] = run; run += d[j]; }
  }
}

// deg variant: off = exclusive scan(deg), dinv = rsqrt(deg+1), off[n] = e
__global__ __launch_bounds__(256) void k_scan_deg(const int* __restrict__ deg,
                                                  const int* __restrict__ partials,
                                                  int* __restrict__ off,
                                                  float* __restrict__ dinv, int n, int e) {
  __shared__ int red[256];
  int t = threadIdx.x;
  int base = blockIdx.x * SCAN_TILE + t * 4;
  int d[4];
  int s = 0;
#pragma unroll
  for (int j = 0; j < 4; ++j) { int i = base + j; d[j] = (i < n) ? deg[i] : 0; s += d[j]; }
  red[t] = s;
  __syncthreads();
  int incl = s;
  for (int ofs = 1; ofs < 256; ofs <<= 1) {
    int u = (t >= ofs) ? red[t - ofs] : 0;
    __syncthreads();
    red[t] += u;
    __syncthreads();
    incl = red[t];
  }
  int run = partials[blockIdx.x] + incl - s;
#pragma unroll
  for (int j = 0; j < 4; ++j) {
    int i = base + j;
    if (i < n) {
      off[i] = run;
      run += d[j];
      dinv[i] = rsqrtf((float)(d[j] + 1));
    }
  }
  if (blockIdx.x == 0 && t == 0) off[n] = e;
}

// ---------------- binning pass B: scatter pairs into bin-sorted order --------
__global__ __launch_bounds__(256) void k_scatter(const int* __restrict__ src,
                                                 const int* __restrict__ dst,
                                                 const int* __restrict__ scanHist,
                                                 int2* __restrict__ sp, int e, int nblk) {
  __shared__ int cur[NBINS];
  int t = threadIdx.x;
  for (int i = t; i < NBINS; i += 256) cur[i] = scanHist[i * nblk + blockIdx.x];
  __syncthreads();
  int base = blockIdx.x * ETILE;
  for (int i = base + t; i < base + ETILE; i += 256)
    if (i < e) {
      int d = dst[i];
      int pos = atomicAdd(&cur[d >> BIN_SHIFT], 1);
      sp[pos] = make_int2(src[i], d);
    }
}

// ---------------- pass C: per-bin degree count (LDS) ----------------
__global__ __launch_bounds__(256) void k_bindeg(const int2* __restrict__ sp,
                                                const int* __restrict__ scanHist,
                                                int* __restrict__ deg, int n, int e, int nblk) {
  __shared__ int dl[BIN_NODES];
  int b = blockIdx.x, t = threadIdx.x;
  if (t < BIN_NODES) dl[t] = 0;
  __syncthreads();
  int e0 = scanHist[b * nblk];
  int e1 = (b + 1 < NBINS) ? scanHist[(b + 1) * nblk] : e;
  int nbase = b * BIN_NODES;
  for (int i = e0 + t; i < e1; i += 256) atomicAdd(&dl[sp[i].y - nbase], 1);
  __syncthreads();
  int node = nbase + t;
  if (t < BIN_NODES && node < n) deg[node] = dl[t];
}

// ---------------- pass D: per-bin CSR fill (LDS cursors, local writes) -------
__global__ __launch_bounds__(256) void k_binfill(const int2* __restrict__ sp,
                                                 const int* __restrict__ scanHist,
                                                 const int* __restrict__ off,
                                                 int* __restrict__ srcs, int n, int e, int nblk) {
  __shared__ int curl[BIN_NODES];
  __shared__ int offl[BIN_NODES];
  int b = blockIdx.x, t = threadIdx.x;
  int nbase = b * BIN_NODES;
  if (t < BIN_NODES) {
    curl[t] = 0;
    int node = nbase + t;
    offl[t] = (node < n) ? off[node] : 0;
  }
  __syncthreads();
  int e0 = scanHist[b * nblk];
  int e1 = (b + 1 < NBINS) ? scanHist[(b + 1) * nblk] : e;
  for (int i = e0 + t; i < e1; i += 256) {
    int2 p = sp[i];
    int l = p.y - nbase;
    int pos = offl[l] + atomicAdd(&curl[l], 1);
    srcs[pos] = p.x;
  }
}

// ---------------- GEMM: [n,128] @ [128,64] ----------------
__global__ __launch_bounds__(256) void k_gemm_xw1(const float* __restrict__ x,
                                                  const float* __restrict__ W,
                                                  float* __restrict__ out, int n) {
  __shared__ float Ws[DIN * DH];
  __shared__ float xs[32 * 129];
  int t = threadIdx.x;
  for (int i = t; i < DIN * DH; i += 256) Ws[i] = W[i];
  int row0 = blockIdx.x * 32;
  for (int i = t; i < 32 * DIN; i += 256) {
    int r = i >> 7, c = i & 127;
    int gr = row0 + r;
    xs[r * 129 + c] = (gr < n) ? x[gr * DIN + c] : 0.f;
  }
  __syncthreads();
  int r = t >> 3;
  int c0 = (t & 7) * 8;
  float acc[8] = {0, 0, 0, 0, 0, 0, 0, 0};
  for (int k = 0; k < DIN; ++k) {
    float xv = xs[r * 129 + k];
#pragma unroll
    for (int j = 0; j < 8; ++j) acc[j] = fmaf(xv, Ws[k * DH + c0 + j], acc[j]);
  }
  int gr = row0 + r;
  if (gr < n) {
#pragma unroll
    for (int j = 0; j < 8; ++j) out[gr * DH + c0 + j] = acc[j];
  }
}

// ---------------- GEMM: [n,64] @ [64,64] ----------------
__global__ __launch_bounds__(256) void k_gemm64(const float* __restrict__ in,
                                                const float* __restrict__ W,
                                                float* __restrict__ out, int n) {
  __shared__ float Ws[DH * DH];
  __shared__ float xs[64 * 65];
  int t = threadIdx.x;
  for (int i = t; i < DH * DH; i += 256) Ws[i] = W[i];
  int row0 = blockIdx.x * 64;
  for (int i = t; i < 64 * DH; i += 256) {
    int r = i >> 6, c = i & 63;
    int gr = row0 + r;
    xs[r * 65 + c] = (gr < n) ? in[gr * DH + c] : 0.f;
  }
  __syncthreads();
  int r = t >> 2;
  int c0 = (t & 3) * 16;
  float acc[16];
#pragma unroll
  for (int j = 0; j < 16; ++j) acc[j] = 0.f;
  for (int k = 0; k < DH; ++k) {
    float xv = xs[r * 65 + k];
#pragma unroll
    for (int j = 0; j < 16; ++j) acc[j] = fmaf(xv, Ws[k * DH + c0 + j], acc[j]);
  }
  int gr = row0 + r;
  if (gr < n) {
#pragma unroll
    for (int j = 0; j < 16; ++j) out[gr * DH + c0 + j] = acc[j];
  }
}

// ---------------- CSR gather-aggregate, fused self-loop + bias (+relu) ------
__global__ __launch_bounds__(256) void k_agg(const float* __restrict__ h,
                                             const int* __restrict__ off,
                                             const int* __restrict__ srcs,
                                             const float* __restrict__ dinv,
                                             const float* __restrict__ bias,
                                             float* __restrict__ out, int n, int relu) {
  int gid = blockIdx.x * 4 + (threadIdx.x >> 6);
  int d = threadIdx.x & 63;
  if (gid >= n) return;
  gid = __builtin_amdgcn_readfirstlane(gid);
  float di = dinv[gid];
  float acc = h[(size_t)gid * DH + d] * di * di;
  int b0 = off[gid], b1 = off[gid + 1];
  int j = b0;
  for (; j + 4 <= b1; j += 4) {
    int s0 = srcs[j], s1 = srcs[j + 1], s2 = srcs[j + 2], s3 = srcs[j + 3];
    float w0 = dinv[s0] * di, w1 = dinv[s1] * di, w2 = dinv[s2] * di, w3 = dinv[s3] * di;
    float v0 = h[(size_t)s0 * DH + d];
    float v1 = h[(size_t)s1 * DH + d];
    float v2 = h[(size_t)s2 * DH + d];
    float v3 = h[(size_t)s3 * DH + d];
    acc = fmaf(v0, w0, acc);
    acc = fmaf(v1, w1, acc);
    acc = fmaf(v2, w2, acc);
    acc = fmaf(v3, w3, acc);
  }
  for (; j < b1; ++j) {
    int s = srcs[j];
    acc = fmaf(h[(size_t)s * DH + d], dinv[s] * di, acc);
  }
  acc += bias[d];
  if (relu) acc = fmaxf(acc, 0.f);
  out[(size_t)gid * DH + d] = acc;
}

// ---------------- fused MLP head ----------------
__global__ __launch_bounds__(256) void k_mlp(const float* __restrict__ z,
                                             const float* __restrict__ Wp1,
                                             const float* __restrict__ bp1,
                                             const float* __restrict__ Wp2,
                                             const float* __restrict__ bp2,
                                             float* __restrict__ p, int n) {
  __shared__ float W1s[DH * DH];
  __shared__ float W2s[DH * DH];
  __shared__ float xs[64 * 65];
  __shared__ float b1s[64], b2s[64];
  int t = threadIdx.x;
  for (int i = t; i < DH * DH; i += 256) { W1s[i] = Wp1[i]; W2s[i] = Wp2[i]; }
  if (t < 64) { b1s[t] = bp1[t]; b2s[t] = bp2[t]; }
  int row0 = blockIdx.x * 64;
  for (int i = t; i < 64 * DH; i += 256) {
    int r = i >> 6, c = i & 63;
    int gr = row0 + r;
    xs[r * 65 + c] = (gr < n) ? z[gr * DH + c] : 0.f;
  }
  __syncthreads();
  int r = t >> 2;
  int c0 = (t & 3) * 16;
  float acc[16];
#pragma unroll
  for (int j = 0; j < 16; ++j) acc[j] = b1s[c0 + j];
  for (int k = 0; k < DH; ++k) {
    float xv = xs[r * 65 + k];
#pragma unroll
    for (int j = 0; j < 16; ++j) acc[j] = fmaf(xv, W1s[k * DH + c0 + j], acc[j]);
  }
  __syncthreads();
#pragma unroll
  for (int j = 0; j < 16; ++j) xs[r * 65 + c0 + j] = fmaxf(acc[j], 0.f);
  __syncthreads();
#pragma unroll
  for (int j = 0; j < 16; ++j) acc[j] = b2s[c0 + j];
  for (int k = 0; k < DH; ++k) {
    float xv = xs[r * 65 + k];
#pragma unroll
    for (int j = 0; j < 16; ++j) acc[j] = fmaf(xv, W2s[k * DH + c0 + j], acc[j]);
  }
  int gr = row0 + r;
  if (gr < n) {
#pragma unroll
    for (int j = 0; j < 16; ++j) p[gr * DH + c0 + j] = acc[j];
  }
}

extern "C" void kernel_launch(void* const* d_in, const int* in_sizes, int n_in,
                              void* d_out, int out_size, void* d_ws, size_t ws_size,
                              hipStream_t stream) {
  const float* x   = (const float*)d_in[0];
  const int*   ei  = (const int*)d_in[1];
  const float* W1  = (const float*)d_in[2];
  const float* b1  = (const float*)d_in[3];
  const float* W2  = (const float*)d_in[4];
  const float* b2  = (const float*)d_in[5];
  const float* Wp1 = (const float*)d_in[6];
  const float* bp1 = (const float*)d_in[7];
  const float* Wp2 = (const float*)d_in[8];
  const float* bp2 = (const float*)d_in[9];

  int n = in_sizes[0] / DIN;   // 50000
  int e = in_sizes[1] / 2;     // 800000
  const int* src = ei;
  const int* dst = ei + e;

  int nblk = (e + ETILE - 1) / ETILE;           // 196
  int nbBins = (n + BIN_NODES - 1) / BIN_NODES; // 391

  // workspace layout
  char* ws = (char*)d_ws;
  float* bufA    = (float*)ws;                                    // 12.8 MB
  int*   off     = (int*)(ws + ((size_t)13 << 20));               // (n+1) i32, 256K slot
  int*   deg     = (int*)(ws + ((size_t)13 << 20) + (1 << 18));
  float* dinv    = (float*)(ws + ((size_t)13 << 20) + (2 << 18));
  int*   parts   = (int*)(ws + ((size_t)13 << 20) + (3 << 18));   // scan partials (<=256)
  int*   histMat = (int*)(ws + ((size_t)13 << 20) + (4 << 18));   // NBINS*nblk i32 ~400KB (512K slot)
  int2*  sp      = (int2*)(ws + ((size_t)13 << 20) + (6 << 18));  // e int2 = 6.4MB
  int*   srcs    = (int*)(ws + ((size_t)13 << 20) + (6 << 18) + ((size_t)e * 8)); // e i32 = 3.2MB

  float* zout = (float*)d_out;
  float* pout = zout + (size_t)n * DH;

  // ---- binning CSR build ----
  int nHist = NBINS * nblk;                       // 100352
  int nbH = (nHist + SCAN_TILE - 1) / SCAN_TILE;  // 98
  int nbD = (n + SCAN_TILE - 1) / SCAN_TILE;      // 49

  k_hist<<<nblk, 256, 0, stream>>>(dst, histMat, e, nblk);
  k_scan_part<<<nbH, 256, 0, stream>>>(histMat, parts, nHist);
  k_scan_mid<<<1, 256, 0, stream>>>(parts, nbH);
  k_scan_emit<<<nbH, 256, 0, stream>>>(histMat, parts, nHist);
  k_scatter<<<nblk, 256, 0, stream>>>(src, dst, histMat, sp, e, nblk);
  k_bindeg<<<nbBins, 256, 0, stream>>>(sp, histMat, deg, n, e, nblk);
  k_scan_part<<<nbD, 256, 0, stream>>>(deg, parts, n);
  k_scan_mid<<<1, 256, 0, stream>>>(parts, nbD);
  k_scan_deg<<<nbD, 256, 0, stream>>>(deg, parts, off, dinv, n, e);
  k_binfill<<<nbBins, 256, 0, stream>>>(sp, histMat, off, srcs, n, e, nblk);

  // ---- layer 1 ----
  k_gemm_xw1<<<(n + 31) / 32, 256, 0, stream>>>(x, W1, bufA, n);
  k_agg<<<(n + 3) / 4, 256, 0, stream>>>(bufA, off, srcs, dinv, b1, pout, n, 1);

  // ---- layer 2 ----
  k_gemm64<<<(n + 63) / 64, 256, 0, stream>>>(pout, W2, bufA, n);
  k_agg<<<(n + 3) / 4, 256, 0, stream>>>(bufA, off, srcs, dinv, b2, zout, n, 0);

  // ---- head ----
  k_mlp<<<(n + 63) / 64, 256, 0, stream>>>(zout, Wp1, bp1, Wp2, bp2, pout, n);
}

// Round 5
// 176.659 us; speedup vs baseline: 2.8832x; 1.1339x over previous
//
#include <hip/hip_runtime.h>

#define DIN 128
#define DH 64
#define SCAN_TILE 1024
#define NBINS 512      // bin = dst >> 7 ; n=50000 -> bins 0..390 used
#define BIN_SHIFT 7
#define BIN_NODES 128
#define ETILE 4096     // edges per histogram/scatter block

// ---------------- binning pass A: per-block histogram ----------------
__global__ __launch_bounds__(256) void k_hist(const int* __restrict__ dst,
                                              int* __restrict__ histMat, int e, int nblk) {
  __shared__ int h[NBINS];
  int t = threadIdx.x;
  for (int i = t; i < NBINS; i += 256) h[i] = 0;
  __syncthreads();
  int base = blockIdx.x * ETILE;
  for (int i = base + t; i < base + ETILE; i += 256)
    if (i < e) atomicAdd(&h[dst[i] >> BIN_SHIFT], 1);
  __syncthreads();
  for (int i = t; i < NBINS; i += 256) histMat[i * nblk + blockIdx.x] = h[i];
}

// ---------------- generic hierarchical exclusive scan ----------------
__global__ __launch_bounds__(256) void k_scan_part(const int* __restrict__ in,
                                                   int* __restrict__ partials, int n) {
  __shared__ int red[256];
  int t = threadIdx.x;
  int base = blockIdx.x * SCAN_TILE + t * 4;
  int s = 0;
#pragma unroll
  for (int j = 0; j < 4; ++j) { int i = base + j; if (i < n) s += in[i]; }
  red[t] = s;
  __syncthreads();
  for (int ofs = 128; ofs > 0; ofs >>= 1) {
    if (t < ofs) red[t] += red[t + ofs];
    __syncthreads();
  }
  if (t == 0) partials[blockIdx.x] = red[0];
}

__global__ __launch_bounds__(256) void k_scan_mid(int* __restrict__ partials, int nb) {
  __shared__ int sm[256];
  int t = threadIdx.x;
  int v = (t < nb) ? partials[t] : 0;
  sm[t] = v;
  __syncthreads();
  for (int ofs = 1; ofs < 256; ofs <<= 1) {
    int u = (t >= ofs) ? sm[t - ofs] : 0;
    __syncthreads();
    sm[t] += u;
    __syncthreads();
  }
  if (t < nb) partials[t] = sm[t] - v;  // exclusive
}

// in-place exclusive-scan emit
__global__ __launch_bounds__(256) void k_scan_emit(int* __restrict__ data,
                                                   const int* __restrict__ partials, int n) {
  __shared__ int red[256];
  int t = threadIdx.x;
  int base = blockIdx.x * SCAN_TILE + t * 4;
  int d[4];
  int s = 0;
#pragma unroll
  for (int j = 0; j < 4; ++j) { int i = base + j; d[j] = (i < n) ? data[i] : 0; s += d[j]; }
  red[t] = s;
  __syncthreads();
  int incl = s;
  for (int ofs = 1; ofs < 256; ofs <<= 1) {
    int u = (t >= ofs) ? red[t - ofs] : 0;
    __syncthreads();
    red[t] += u;
    __syncthreads();
    incl = red[t];
  }
  int run = partials[blockIdx.x] + incl - s;
#pragma unroll
  for (int j = 0; j < 4; ++j) {
    int i = base + j;
    if (i < n) { data[i] = run; run += d[j]; }
  }
}

// deg variant: off = exclusive scan(deg), dinv = rsqrt(deg+1), off[n] = e
__global__ __launch_bounds__(256) void k_scan_deg(const int* __restrict__ deg,
                                                  const int* __restrict__ partials,
                                                  int* __restrict__ off,
                                                  float* __restrict__ dinv, int n, int e) {
  __shared__ int red[256];
  int t = threadIdx.x;
  int base = blockIdx.x * SCAN_TILE + t * 4;
  int d[4];
  int s = 0;
#pragma unroll
  for (int j = 0; j < 4; ++j) { int i = base + j; d[j] = (i < n) ? deg[i] : 0; s += d[j]; }
  red[t] = s;
  __syncthreads();
  int incl = s;
  for (int ofs = 1; ofs < 256; ofs <<= 1) {
    int u = (t >= ofs) ? red[t - ofs] : 0;
    __syncthreads();
    red[t] += u;
    __syncthreads();
    incl = red[t];
  }
  int run = partials[blockIdx.x] + incl - s;
#pragma unroll
  for (int j = 0; j < 4; ++j) {
    int i = base + j;
    if (i < n) {
      off[i] = run;
      run += d[j];
      dinv[i] = rsqrtf((float)(d[j] + 1));
    }
  }
  if (blockIdx.x == 0 && t == 0) off[n] = e;
}

// ---------------- binning pass B: scatter packed (src<<7|local) --------------
__global__ __launch_bounds__(256) void k_scatter(const int* __restrict__ src,
                                                 const int* __restrict__ dst,
                                                 const int* __restrict__ scanHist,
                                                 int* __restrict__ sp, int e, int nblk) {
  __shared__ int cur[NBINS];
  int t = threadIdx.x;
  for (int i = t; i < NBINS; i += 256) cur[i] = scanHist[i * nblk + blockIdx.x];
  __syncthreads();
  int base = blockIdx.x * ETILE;
  for (int i = base + t; i < base + ETILE; i += 256)
    if (i < e) {
      int d = dst[i];
      int pos = atomicAdd(&cur[d >> BIN_SHIFT], 1);
      sp[pos] = (src[i] << BIN_SHIFT) | (d & (BIN_NODES - 1));
    }
}

// ---------------- pass C: per-bin degree count (LDS) ----------------
__global__ __launch_bounds__(256) void k_bindeg(const int* __restrict__ sp,
                                                const int* __restrict__ scanHist,
                                                int* __restrict__ deg, int n, int e, int nblk) {
  __shared__ int dl[BIN_NODES];
  int b = blockIdx.x, t = threadIdx.x;
  if (t < BIN_NODES) dl[t] = 0;
  __syncthreads();
  int e0 = scanHist[b * nblk];
  int e1 = (b + 1 < NBINS) ? scanHist[(b + 1) * nblk] : e;
  for (int i = e0 + t; i < e1; i += 256) atomicAdd(&dl[sp[i] & (BIN_NODES - 1)], 1);
  __syncthreads();
  int node = b * BIN_NODES + t;
  if (t < BIN_NODES && node < n) deg[node] = dl[t];
}

// ---------------- pass D: per-bin CSR fill ----------------
__global__ __launch_bounds__(256) void k_binfill(const int* __restrict__ sp,
                                                 const int* __restrict__ scanHist,
                                                 const int* __restrict__ off,
                                                 int* __restrict__ srcs, int n, int e, int nblk) {
  __shared__ int curl[BIN_NODES];
  __shared__ int offl[BIN_NODES];
  int b = blockIdx.x, t = threadIdx.x;
  int nbase = b * BIN_NODES;
  if (t < BIN_NODES) {
    curl[t] = 0;
    int node = nbase + t;
    offl[t] = (node < n) ? off[node] : 0;
  }
  __syncthreads();
  int e0 = scanHist[b * nblk];
  int e1 = (b + 1 < NBINS) ? scanHist[(b + 1) * nblk] : e;
  for (int i = e0 + t; i < e1; i += 256) {
    int u = sp[i];
    int l = u & (BIN_NODES - 1);
    int pos = offl[l] + atomicAdd(&curl[l], 1);
    srcs[pos] = u >> BIN_SHIFT;
  }
}

// ---------------- register-tiled GEMM: [n,K] @ [K,64] (+bias,+relu) ----------
// 256 thr, tile 128 rows x 64 cols, per-thread 8 rows x 4 cols.
template <int K, bool RELU, bool BIAS>
__global__ __launch_bounds__(256) void k_gemm_rt(const float* __restrict__ A,
                                                 const float* __restrict__ W,
                                                 const float* __restrict__ bias,
                                                 float* __restrict__ out, int n) {
  constexpr int KC = 32;
  constexpr int MP = 132;  // 128 + 4 pad
  __shared__ float xsT[KC][MP];
  __shared__ float ws[KC * 64];
  __shared__ float bs[64];
  int t = threadIdx.x;
  if (BIAS && t < 64) bs[t] = bias[t];
  int row0 = blockIdx.x * 128;
  int rg = t >> 4;       // 0..15
  int cg = t & 15;       // 0..15
  int r0 = rg * 8;
  int c0 = cg * 4;
  float4 acc[8];
#pragma unroll
  for (int i = 0; i < 8; ++i) acc[i] = make_float4(0.f, 0.f, 0.f, 0.f);

  int lr = t >> 3;  // staging row 0..31
  int kq = t & 7;   // staging k-quad

  for (int kc = 0; kc < K; kc += KC) {
    // stage x chunk transposed: xsT[k'][row]
#pragma unroll
    for (int it = 0; it < 4; ++it) {
      int r = it * 32 + lr;
      int gr = row0 + r;
      float4 v = make_float4(0.f, 0.f, 0.f, 0.f);
      if (gr < n) v = *(const float4*)&A[(size_t)gr * K + kc + kq * 4];
      xsT[kq * 4 + 0][r] = v.x;
      xsT[kq * 4 + 1][r] = v.y;
      xsT[kq * 4 + 2][r] = v.z;
      xsT[kq * 4 + 3][r] = v.w;
    }
    // stage W chunk (contiguous)
#pragma unroll
    for (int j = 0; j < 8; ++j) {
      int idx = t + j * 256;
      ws[idx] = W[(size_t)kc * 64 + idx];
    }
    __syncthreads();
#pragma unroll
    for (int k = 0; k < KC; ++k) {
      float4 xa = *(const float4*)&xsT[k][r0];
      float4 xb = *(const float4*)&xsT[k][r0 + 4];
      float4 wv = *(const float4*)&ws[k * 64 + c0];
      float xr[8] = {xa.x, xa.y, xa.z, xa.w, xb.x, xb.y, xb.z, xb.w};
#pragma unroll
      for (int i = 0; i < 8; ++i) {
        acc[i].x = fmaf(xr[i], wv.x, acc[i].x);
        acc[i].y = fmaf(xr[i], wv.y, acc[i].y);
        acc[i].z = fmaf(xr[i], wv.z, acc[i].z);
        acc[i].w = fmaf(xr[i], wv.w, acc[i].w);
      }
    }
    __syncthreads();
  }

  float4 bv = make_float4(0.f, 0.f, 0.f, 0.f);
  if (BIAS) bv = *(const float4*)&bs[c0];
#pragma unroll
  for (int i = 0; i < 8; ++i) {
    int gr = row0 + r0 + i;
    if (gr < n) {
      float4 o = acc[i];
      o.x += bv.x; o.y += bv.y; o.z += bv.z; o.w += bv.w;
      if (RELU) {
        o.x = fmaxf(o.x, 0.f); o.y = fmaxf(o.y, 0.f);
        o.z = fmaxf(o.z, 0.f); o.w = fmaxf(o.w, 0.f);
      }
      *(float4*)&out[(size_t)gr * 64 + c0] = o;
    }
  }
}

// ---------------- CSR gather-aggregate: float4/lane, 4 edges in flight -------
__global__ __launch_bounds__(256) void k_agg(const float* __restrict__ h,
                                             const int* __restrict__ off,
                                             const int* __restrict__ srcs,
                                             const float* __restrict__ dinv,
                                             const float* __restrict__ bias,
                                             float* __restrict__ out, int n, int relu) {
  int gid = blockIdx.x * 4 + (threadIdx.x >> 6);
  if (gid >= n) return;
  gid = __builtin_amdgcn_readfirstlane(gid);
  int lane = threadIdx.x & 63;
  int grp = lane >> 4;         // 0..3: edge slot
  int d4 = (lane & 15) * 4;    // feature quad
  float di = dinv[gid];
  float4 acc = make_float4(0.f, 0.f, 0.f, 0.f);
  if (grp == 0) {  // self-loop counted once
    float4 hv = *(const float4*)&h[(size_t)gid * DH + d4];
    float s = di * di;
    acc.x = hv.x * s; acc.y = hv.y * s; acc.z = hv.z * s; acc.w = hv.w * s;
  }
  int b0 = off[gid], b1 = off[gid + 1];
  int j = b0 + grp;
  for (; j + 4 < b1; j += 8) {
    int sa = srcs[j], sb = srcs[j + 4];
    float wa = dinv[sa] * di, wb = dinv[sb] * di;
    float4 va = *(const float4*)&h[(size_t)sa * DH + d4];
    float4 vb = *(const float4*)&h[(size_t)sb * DH + d4];
    acc.x = fmaf(va.x, wa, acc.x); acc.y = fmaf(va.y, wa, acc.y);
    acc.z = fmaf(va.z, wa, acc.z); acc.w = fmaf(va.w, wa, acc.w);
    acc.x = fmaf(vb.x, wb, acc.x); acc.y = fmaf(vb.y, wb, acc.y);
    acc.z = fmaf(vb.z, wb, acc.z); acc.w = fmaf(vb.w, wb, acc.w);
  }
  if (j < b1) {
    int s = srcs[j];
    float w = dinv[s] * di;
    float4 v = *(const float4*)&h[(size_t)s * DH + d4];
    acc.x = fmaf(v.x, w, acc.x); acc.y = fmaf(v.y, w, acc.y);
    acc.z = fmaf(v.z, w, acc.z); acc.w = fmaf(v.w, w, acc.w);
  }
  // reduce across the 4 edge-slot groups (d4 preserved under xor 16/32)
  acc.x += __shfl_xor(acc.x, 16, 64); acc.x += __shfl_xor(acc.x, 32, 64);
  acc.y += __shfl_xor(acc.y, 16, 64); acc.y += __shfl_xor(acc.y, 32, 64);
  acc.z += __shfl_xor(acc.z, 16, 64); acc.z += __shfl_xor(acc.z, 32, 64);
  acc.w += __shfl_xor(acc.w, 16, 64); acc.w += __shfl_xor(acc.w, 32, 64);
  if (lane < 16) {
    float4 bv = *(const float4*)&bias[d4];
    acc.x += bv.x; acc.y += bv.y; acc.z += bv.z; acc.w += bv.w;
    if (relu) {
      acc.x = fmaxf(acc.x, 0.f); acc.y = fmaxf(acc.y, 0.f);
      acc.z = fmaxf(acc.z, 0.f); acc.w = fmaxf(acc.w, 0.f);
    }
    *(float4*)&out[(size_t)gid * DH + d4] = acc;
  }
}

extern "C" void kernel_launch(void* const* d_in, const int* in_sizes, int n_in,
                              void* d_out, int out_size, void* d_ws, size_t ws_size,
                              hipStream_t stream) {
  const float* x   = (const float*)d_in[0];
  const int*   ei  = (const int*)d_in[1];
  const float* W1  = (const float*)d_in[2];
  const float* b1  = (const float*)d_in[3];
  const float* W2  = (const float*)d_in[4];
  const float* b2  = (const float*)d_in[5];
  const float* Wp1 = (const float*)d_in[6];
  const float* bp1 = (const float*)d_in[7];
  const float* Wp2 = (const float*)d_in[8];
  const float* bp2 = (const float*)d_in[9];

  int n = in_sizes[0] / DIN;   // 50000
  int e = in_sizes[1] / 2;     // 800000
  const int* src = ei;
  const int* dst = ei + e;

  int nblk = (e + ETILE - 1) / ETILE;           // 196
  int nbBins = (n + BIN_NODES - 1) / BIN_NODES; // 391

  // workspace layout
  char* ws = (char*)d_ws;
  float* bufA    = (float*)ws;                                    // 12.8 MB
  int*   off     = (int*)(ws + ((size_t)13 << 20));
  int*   deg     = (int*)(ws + ((size_t)13 << 20) + (1 << 18));
  float* dinv    = (float*)(ws + ((size_t)13 << 20) + (2 << 18));
  int*   parts   = (int*)(ws + ((size_t)13 << 20) + (3 << 18));
  int*   histMat = (int*)(ws + ((size_t)13 << 20) + (4 << 18));   // ~400KB
  int*   sp      = (int*)(ws + ((size_t)13 << 20) + (6 << 18));   // e i32 = 3.2MB
  int*   srcs    = sp + e;                                        // e i32 = 3.2MB

  float* zout = (float*)d_out;
  float* pout = zout + (size_t)n * DH;

  int nHist = NBINS * nblk;
  int nbH = (nHist + SCAN_TILE - 1) / SCAN_TILE;
  int nbD = (n + SCAN_TILE - 1) / SCAN_TILE;
  int gG = (n + 127) / 128;  // 391

  // ---- binning CSR build ----
  k_hist<<<nblk, 256, 0, stream>>>(dst, histMat, e, nblk);
  k_scan_part<<<nbH, 256, 0, stream>>>(histMat, parts, nHist);
  k_scan_mid<<<1, 256, 0, stream>>>(parts, nbH);
  k_scan_emit<<<nbH, 256, 0, stream>>>(histMat, parts, nHist);
  k_scatter<<<nblk, 256, 0, stream>>>(src, dst, histMat, sp, e, nblk);
  k_bindeg<<<nbBins, 256, 0, stream>>>(sp, histMat, deg, n, e, nblk);
  k_scan_part<<<nbD, 256, 0, stream>>>(deg, parts, n);
  k_scan_mid<<<1, 256, 0, stream>>>(parts, nbD);
  k_scan_deg<<<nbD, 256, 0, stream>>>(deg, parts, off, dinv, n, e);
  k_binfill<<<nbBins, 256, 0, stream>>>(sp, histMat, off, srcs, n, e, nblk);

  // ---- layer 1: h = relu(agg(x@W1) + b1) -> pout ----
  k_gemm_rt<DIN, false, false><<<gG, 256, 0, stream>>>(x, W1, nullptr, bufA, n);
  k_agg<<<(n + 3) / 4, 256, 0, stream>>>(bufA, off, srcs, dinv, b1, pout, n, 1);

  // ---- layer 2: z = agg(h@W2) + b2 -> zout ----
  k_gemm_rt<DH, false, false><<<gG, 256, 0, stream>>>(pout, W2, nullptr, bufA, n);
  k_agg<<<(n + 3) / 4, 256, 0, stream>>>(bufA, off, srcs, dinv, b2, zout, n, 0);

  // ---- head: T = relu(z@Wp1+bp1) -> bufA ; p = T@Wp2+bp2 -> pout ----
  k_gemm_rt<DH, true, true><<<gG, 256, 0, stream>>>(zout, Wp1, bp1, bufA, n);
  k_gemm_rt<DH, false, true><<<gG, 256, 0, stream>>>(bufA, Wp2, bp2, pout, n);
}

// Round 6
// 150.364 us; speedup vs baseline: 3.3874x; 1.1749x over previous
//
#include <hip/hip_runtime.h>
#include <hip/hip_fp16.h>

#define DIN 128
#define DH 64
#define SCAN_TILE 1024
#define NBINS 512      // bin = dst >> 7 ; n=50000 -> bins 0..390 used
#define BIN_SHIFT 7
#define BIN_NODES 128
#define ETILE 4096     // edges per histogram/scatter block
#define EBUF 4096      // LDS edge buffer per bin (avg fill ~2046)

__device__ inline unsigned pack_half2(float a, float b) {
  __half2 h = __floats2half2_rn(a, b);
  return *(unsigned*)&h;
}
__device__ inline float2 unpack_half2(unsigned u) {
  __half2 h = *(__half2*)&u;
  return __half22float2(h);
}

// ---------------- binning pass A: per-block histogram ----------------
__global__ __launch_bounds__(256) void k_hist(const int* __restrict__ dst,
                                              int* __restrict__ histMat, int e, int nblk) {
  __shared__ int h[NBINS];
  int t = threadIdx.x;
  for (int i = t; i < NBINS; i += 256) h[i] = 0;
  __syncthreads();
  int base = blockIdx.x * ETILE;
  for (int i = base + t; i < base + ETILE; i += 256)
    if (i < e) atomicAdd(&h[dst[i] >> BIN_SHIFT], 1);
  __syncthreads();
  for (int i = t; i < NBINS; i += 256) histMat[i * nblk + blockIdx.x] = h[i];
}

// ---------------- hierarchical exclusive scan (histMat) ----------------
__global__ __launch_bounds__(256) void k_scan_part(const int* __restrict__ in,
                                                   int* __restrict__ partials, int n) {
  __shared__ int red[256];
  int t = threadIdx.x;
  int base = blockIdx.x * SCAN_TILE + t * 4;
  int s = 0;
#pragma unroll
  for (int j = 0; j < 4; ++j) { int i = base + j; if (i < n) s += in[i]; }
  red[t] = s;
  __syncthreads();
  for (int ofs = 128; ofs > 0; ofs >>= 1) {
    if (t < ofs) red[t] += red[t + ofs];
    __syncthreads();
  }
  if (t == 0) partials[blockIdx.x] = red[0];
}

__global__ __launch_bounds__(256) void k_scan_mid(int* __restrict__ partials, int nb) {
  __shared__ int sm[256];
  int t = threadIdx.x;
  int v = (t < nb) ? partials[t] : 0;
  sm[t] = v;
  __syncthreads();
  for (int ofs = 1; ofs < 256; ofs <<= 1) {
    int u = (t >= ofs) ? sm[t - ofs] : 0;
    __syncthreads();
    sm[t] += u;
    __syncthreads();
  }
  if (t < nb) partials[t] = sm[t] - v;  // exclusive
}

__global__ __launch_bounds__(256) void k_scan_emit(int* __restrict__ data,
                                                   const int* __restrict__ partials, int n) {
  __shared__ int red[256];
  int t = threadIdx.x;
  int base = blockIdx.x * SCAN_TILE + t * 4;
  int d[4];
  int s = 0;
#pragma unroll
  for (int j = 0; j < 4; ++j) { int i = base + j; d[j] = (i < n) ? data[i] : 0; s += d[j]; }
  red[t] = s;
  __syncthreads();
  int incl = s;
  for (int ofs = 1; ofs < 256; ofs <<= 1) {
    int u = (t >= ofs) ? red[t - ofs] : 0;
    __syncthreads();
    red[t] += u;
    __syncthreads();
    incl = red[t];
  }
  int run = partials[blockIdx.x] + incl - s;
#pragma unroll
  for (int j = 0; j < 4; ++j) {
    int i = base + j;
    if (i < n) { data[i] = run; run += d[j]; }
  }
}

// ---------------- binning pass B: scatter packed (src<<7|local) --------------
__global__ __launch_bounds__(256) void k_scatter(const int* __restrict__ src,
                                                 const int* __restrict__ dst,
                                                 const int* __restrict__ scanHist,
                                                 int* __restrict__ sp, int e, int nblk) {
  __shared__ int cur[NBINS];
  int t = threadIdx.x;
  for (int i = t; i < NBINS; i += 256) cur[i] = scanHist[i * nblk + blockIdx.x];
  __syncthreads();
  int base = blockIdx.x * ETILE;
  for (int i = base + t; i < base + ETILE; i += 256)
    if (i < e) {
      int d = dst[i];
      int pos = atomicAdd(&cur[d >> BIN_SHIFT], 1);
      sp[pos] = (src[i] << BIN_SHIFT) | (d & (BIN_NODES - 1));
    }
}

// ---------------- pass C (fused): per-bin deg + local scan -> off/dinv/srcs --
__global__ __launch_bounds__(256) void k_bincsr(const int* __restrict__ sp,
                                                const int* __restrict__ scanHist,
                                                int* __restrict__ off,
                                                float* __restrict__ dinv,
                                                int* __restrict__ srcs,
                                                int n, int e, int nblk) {
  __shared__ int dl[BIN_NODES];
  __shared__ int sc[BIN_NODES];
  __shared__ int curl[BIN_NODES];
  __shared__ int ebuf[EBUF];
  int b = blockIdx.x, t = threadIdx.x;
  if (t < BIN_NODES) dl[t] = 0;
  __syncthreads();
  int e0 = scanHist[b * nblk];
  int e1 = (b + 1 < NBINS) ? scanHist[(b + 1) * nblk] : e;
  for (int i = e0 + t; i < e1; i += 256) {
    int u = sp[i];
    int k = i - e0;
    if (k < EBUF) ebuf[k] = u;
    atomicAdd(&dl[u & (BIN_NODES - 1)], 1);
  }
  __syncthreads();
  if (t < BIN_NODES) sc[t] = dl[t];
  __syncthreads();
  for (int ofs = 1; ofs < BIN_NODES; ofs <<= 1) {
    int v = (t < BIN_NODES && t >= ofs) ? sc[t - ofs] : 0;
    __syncthreads();
    if (t < BIN_NODES) sc[t] += v;
    __syncthreads();
  }
  int nbase = b * BIN_NODES;
  if (t < BIN_NODES) {
    int ex = e0 + sc[t] - dl[t];  // global CSR start for this node
    curl[t] = ex;
    int node = nbase + t;
    if (node < n) {
      off[node] = ex;
      dinv[node] = rsqrtf((float)(dl[t] + 1));
    }
  }
  if (b == 0 && t == 0) off[n] = e;
  __syncthreads();
  for (int i = e0 + t; i < e1; i += 256) {
    int k = i - e0;
    int u = (k < EBUF) ? ebuf[k] : sp[i];
    int l = u & (BIN_NODES - 1);
    int pos = atomicAdd(&curl[l], 1);
    srcs[pos] = u >> BIN_SHIFT;
  }
}

// ---------------- register-tiled GEMM: [n,K] @ [K,64] (+bias,+relu) ----------
// 256 thr, tile 128 rows x 64 cols, per-thread 8 rows x 4 cols.
// OUTHALF: write __half instead of float (for gather tables).
template <int K, bool RELU, bool BIAS, bool OUTHALF>
__global__ __launch_bounds__(256) void k_gemm_rt(const float* __restrict__ A,
                                                 const float* __restrict__ W,
                                                 const float* __restrict__ bias,
                                                 void* __restrict__ outv, int n) {
  constexpr int KC = 32;
  constexpr int MP = 132;  // 128 + 4 pad
  __shared__ float xsT[KC][MP];
  __shared__ float ws[KC * 64];
  __shared__ float bs[64];
  int t = threadIdx.x;
  if (BIAS && t < 64) bs[t] = bias[t];
  int row0 = blockIdx.x * 128;
  int rg = t >> 4;
  int cg = t & 15;
  int r0 = rg * 8;
  int c0 = cg * 4;
  float4 acc[8];
#pragma unroll
  for (int i = 0; i < 8; ++i) acc[i] = make_float4(0.f, 0.f, 0.f, 0.f);

  int lr = t >> 3;  // staging row 0..31
  int kq = t & 7;   // staging k-quad

  for (int kc = 0; kc < K; kc += KC) {
#pragma unroll
    for (int it = 0; it < 4; ++it) {
      int r = it * 32 + lr;
      int gr = row0 + r;
      float4 v = make_float4(0.f, 0.f, 0.f, 0.f);
      if (gr < n) v = *(const float4*)&A[(size_t)gr * K + kc + kq * 4];
      xsT[kq * 4 + 0][r] = v.x;
      xsT[kq * 4 + 1][r] = v.y;
      xsT[kq * 4 + 2][r] = v.z;
      xsT[kq * 4 + 3][r] = v.w;
    }
#pragma unroll
    for (int j = 0; j < 8; ++j) {
      int idx = t + j * 256;
      ws[idx] = W[(size_t)kc * 64 + idx];
    }
    __syncthreads();
#pragma unroll
    for (int k = 0; k < KC; ++k) {
      float4 xa = *(const float4*)&xsT[k][r0];
      float4 xb = *(const float4*)&xsT[k][r0 + 4];
      float4 wv = *(const float4*)&ws[k * 64 + c0];
      float xr[8] = {xa.x, xa.y, xa.z, xa.w, xb.x, xb.y, xb.z, xb.w};
#pragma unroll
      for (int i = 0; i < 8; ++i) {
        acc[i].x = fmaf(xr[i], wv.x, acc[i].x);
        acc[i].y = fmaf(xr[i], wv.y, acc[i].y);
        acc[i].z = fmaf(xr[i], wv.z, acc[i].z);
        acc[i].w = fmaf(xr[i], wv.w, acc[i].w);
      }
    }
    __syncthreads();
  }

  float4 bv = make_float4(0.f, 0.f, 0.f, 0.f);
  if (BIAS) bv = *(const float4*)&bs[c0];
#pragma unroll
  for (int i = 0; i < 8; ++i) {
    int gr = row0 + r0 + i;
    if (gr < n) {
      float4 o = acc[i];
      o.x += bv.x; o.y += bv.y; o.z += bv.z; o.w += bv.w;
      if (RELU) {
        o.x = fmaxf(o.x, 0.f); o.y = fmaxf(o.y, 0.f);
        o.z = fmaxf(o.z, 0.f); o.w = fmaxf(o.w, 0.f);
      }
      if (OUTHALF) {
        uint2 u;
        u.x = pack_half2(o.x, o.y);
        u.y = pack_half2(o.z, o.w);
        *(uint2*)&((__half*)outv)[(size_t)gr * 64 + c0] = u;
      } else {
        *(float4*)&((float*)outv)[(size_t)gr * 64 + c0] = o;
      }
    }
  }
}

// ---------------- CSR gather-aggregate (fp16 table): 4 edges in flight -------
__global__ __launch_bounds__(256) void k_agg(const __half* __restrict__ gh,
                                             const int* __restrict__ off,
                                             const int* __restrict__ srcs,
                                             const float* __restrict__ dinv,
                                             const float* __restrict__ bias,
                                             float* __restrict__ out, int n, int relu) {
  int gid = blockIdx.x * 4 + (threadIdx.x >> 6);
  if (gid >= n) return;
  gid = __builtin_amdgcn_readfirstlane(gid);
  int lane = threadIdx.x & 63;
  int grp = lane >> 4;         // 0..3: edge slot
  int d4 = (lane & 15) * 4;    // feature quad
  float di = dinv[gid];
  float4 acc = make_float4(0.f, 0.f, 0.f, 0.f);
  if (grp == 0) {  // self-loop counted once
    uint2 raw = *(const uint2*)(gh + (size_t)gid * DH + d4);
    float2 f0 = unpack_half2(raw.x), f1 = unpack_half2(raw.y);
    float s = di * di;
    acc.x = f0.x * s; acc.y = f0.y * s; acc.z = f1.x * s; acc.w = f1.y * s;
  }
  int b0 = off[gid], b1 = off[gid + 1];
  int j = b0 + grp;
  for (; j + 4 < b1; j += 8) {
    int sa = srcs[j], sb = srcs[j + 4];
    float wa = dinv[sa] * di, wb = dinv[sb] * di;
    uint2 ra = *(const uint2*)(gh + (size_t)sa * DH + d4);
    uint2 rb = *(const uint2*)(gh + (size_t)sb * DH + d4);
    float2 a0 = unpack_half2(ra.x), a1 = unpack_half2(ra.y);
    float2 b0f = unpack_half2(rb.x), b1f = unpack_half2(rb.y);
    acc.x = fmaf(a0.x, wa, acc.x); acc.y = fmaf(a0.y, wa, acc.y);
    acc.z = fmaf(a1.x, wa, acc.z); acc.w = fmaf(a1.y, wa, acc.w);
    acc.x = fmaf(b0f.x, wb, acc.x); acc.y = fmaf(b0f.y, wb, acc.y);
    acc.z = fmaf(b1f.x, wb, acc.z); acc.w = fmaf(b1f.y, wb, acc.w);
  }
  if (j < b1) {
    int s = srcs[j];
    float w = dinv[s] * di;
    uint2 r = *(const uint2*)(gh + (size_t)s * DH + d4);
    float2 f0 = unpack_half2(r.x), f1 = unpack_half2(r.y);
    acc.x = fmaf(f0.x, w, acc.x); acc.y = fmaf(f0.y, w, acc.y);
    acc.z = fmaf(f1.x, w, acc.z); acc.w = fmaf(f1.y, w, acc.w);
  }
  acc.x += __shfl_xor(acc.x, 16, 64); acc.x += __shfl_xor(acc.x, 32, 64);
  acc.y += __shfl_xor(acc.y, 16, 64); acc.y += __shfl_xor(acc.y, 32, 64);
  acc.z += __shfl_xor(acc.z, 16, 64); acc.z += __shfl_xor(acc.z, 32, 64);
  acc.w += __shfl_xor(acc.w, 16, 64); acc.w += __shfl_xor(acc.w, 32, 64);
  if (lane < 16) {
    float4 bv = *(const float4*)&bias[d4];
    acc.x += bv.x; acc.y += bv.y; acc.z += bv.z; acc.w += bv.w;
    if (relu) {
      acc.x = fmaxf(acc.x, 0.f); acc.y = fmaxf(acc.y, 0.f);
      acc.z = fmaxf(acc.z, 0.f); acc.w = fmaxf(acc.w, 0.f);
    }
    *(float4*)&out[(size_t)gid * DH + d4] = acc;
  }
}

extern "C" void kernel_launch(void* const* d_in, const int* in_sizes, int n_in,
                              void* d_out, int out_size, void* d_ws, size_t ws_size,
                              hipStream_t stream) {
  const float* x   = (const float*)d_in[0];
  const int*   ei  = (const int*)d_in[1];
  const float* W1  = (const float*)d_in[2];
  const float* b1  = (const float*)d_in[3];
  const float* W2  = (const float*)d_in[4];
  const float* b2  = (const float*)d_in[5];
  const float* Wp1 = (const float*)d_in[6];
  const float* bp1 = (const float*)d_in[7];
  const float* Wp2 = (const float*)d_in[8];
  const float* bp2 = (const float*)d_in[9];

  int n = in_sizes[0] / DIN;   // 50000
  int e = in_sizes[1] / 2;     // 800000
  const int* src = ei;
  const int* dst = ei + e;

  int nblk = (e + ETILE - 1) / ETILE;           // 196
  int nbBins = (n + BIN_NODES - 1) / BIN_NODES; // 391

  // workspace layout
  char* ws = (char*)d_ws;
  __half* gtab   = (__half*)ws;                                   // n*64 fp16 = 6.4MB (g1,g2)
  float*  tbuf   = (float*)ws;                                    // n*64 f32 = 12.8MB (head T)
  int*    off    = (int*)(ws + ((size_t)13 << 20));
  float*  dinv   = (float*)(ws + ((size_t)13 << 20) + (1 << 18));
  int*    parts  = (int*)(ws + ((size_t)13 << 20) + (2 << 18));
  int*    histMat= (int*)(ws + ((size_t)13 << 20) + (3 << 18));   // ~392KB
  int*    sp     = (int*)(ws + ((size_t)13 << 20) + (5 << 18));   // e i32 = 3.2MB
  int*    srcs   = sp + e;                                        // e i32 = 3.2MB

  float* zout = (float*)d_out;
  float* pout = zout + (size_t)n * DH;  // scratch for h, then final p

  int nHist = NBINS * nblk;
  int nbH = (nHist + SCAN_TILE - 1) / SCAN_TILE;
  int gG = (n + 127) / 128;  // 391

  // ---- binning CSR build ----
  k_hist<<<nblk, 256, 0, stream>>>(dst, histMat, e, nblk);
  k_scan_part<<<nbH, 256, 0, stream>>>(histMat, parts, nHist);
  k_scan_mid<<<1, 256, 0, stream>>>(parts, nbH);
  k_scan_emit<<<nbH, 256, 0, stream>>>(histMat, parts, nHist);
  k_scatter<<<nblk, 256, 0, stream>>>(src, dst, histMat, sp, e, nblk);
  k_bincsr<<<nbBins, 256, 0, stream>>>(sp, histMat, off, dinv, srcs, n, e, nblk);

  // ---- layer 1: g1 = x@W1 (fp16) ; h = relu(agg(g1) + b1) -> pout ----
  k_gemm_rt<DIN, false, false, true><<<gG, 256, 0, stream>>>(x, W1, nullptr, gtab, n);
  k_agg<<<(n + 3) / 4, 256, 0, stream>>>(gtab, off, srcs, dinv, b1, pout, n, 1);

  // ---- layer 2: g2 = h@W2 (fp16) ; z = agg(g2) + b2 -> zout ----
  k_gemm_rt<DH, false, false, true><<<gG, 256, 0, stream>>>(pout, W2, nullptr, gtab, n);
  k_agg<<<(n + 3) / 4, 256, 0, stream>>>(gtab, off, srcs, dinv, b2, zout, n, 0);

  // ---- head: T = relu(z@Wp1+bp1) -> tbuf ; p = T@Wp2+bp2 -> pout ----
  k_gemm_rt<DH, true, true, false><<<gG, 256, 0, stream>>>(zout, Wp1, bp1, tbuf, n);
  k_gemm_rt<DH, false, true, false><<<gG, 256, 0, stream>>>(tbuf, Wp2, bp2, pout, n);
}